// Round 2
// baseline (634.139 us; speedup 1.0000x reference)
//
#include <hip/hip_runtime.h>
#include <stdint.h>

// PointerNetwork forward, MI355X/gfx950.
// Key decomposition: x-chain and h-chain are independent of sampling;
// scores for unvisited slots are independent of WHICH slots are visited.
// => precompute everything; sampling is a cheap 64-step wave loop.
//
// B=256 batch, S=64 slots/steps, H=128.
//
// RNG: JAX threefry2x32, *partitionable* mode (default since jax 0.4.36):
//   bits[j] = o0 ^ o1 of threefry2x32(step_key, (hi32(j)=0, lo32(j)=j)).
// fold_in(key(42), i) keeps the legacy path: threefry2x32((0,42),(0,i)).

#define BN 256
#define SN 64
#define HN 128
#define NEGV (-1.0e9f)
#define TINYF 1.17549435e-38f

// ---------------- threefry-2x32 (bit-exact JAX) ----------------
__device__ __forceinline__ uint32_t rotl32(uint32_t v, int d) {
  return (v << d) | (v >> (32 - d));
}

__device__ __forceinline__ void threefry2x32(uint32_t k0, uint32_t k1,
                                             uint32_t x0, uint32_t x1,
                                             uint32_t& o0, uint32_t& o1) {
  uint32_t ks2 = k0 ^ k1 ^ 0x1BD11BDAu;
  x0 += k0; x1 += k1;
  // round group 1 (R0 = 13,15,26,6)
  x0 += x1; x1 = rotl32(x1, 13); x1 ^= x0;
  x0 += x1; x1 = rotl32(x1, 15); x1 ^= x0;
  x0 += x1; x1 = rotl32(x1, 26); x1 ^= x0;
  x0 += x1; x1 = rotl32(x1, 6);  x1 ^= x0;
  x0 += k1; x1 += ks2 + 1u;
  // group 2 (R1 = 17,29,16,24)
  x0 += x1; x1 = rotl32(x1, 17); x1 ^= x0;
  x0 += x1; x1 = rotl32(x1, 29); x1 ^= x0;
  x0 += x1; x1 = rotl32(x1, 16); x1 ^= x0;
  x0 += x1; x1 = rotl32(x1, 24); x1 ^= x0;
  x0 += ks2; x1 += k0 + 2u;
  // group 3 (R0)
  x0 += x1; x1 = rotl32(x1, 13); x1 ^= x0;
  x0 += x1; x1 = rotl32(x1, 15); x1 ^= x0;
  x0 += x1; x1 = rotl32(x1, 26); x1 ^= x0;
  x0 += x1; x1 = rotl32(x1, 6);  x1 ^= x0;
  x0 += k0; x1 += k1 + 3u;
  // group 4 (R1)
  x0 += x1; x1 = rotl32(x1, 17); x1 ^= x0;
  x0 += x1; x1 = rotl32(x1, 29); x1 ^= x0;
  x0 += x1; x1 = rotl32(x1, 16); x1 ^= x0;
  x0 += x1; x1 = rotl32(x1, 24); x1 ^= x0;
  x0 += k1; x1 += ks2 + 4u;
  // group 5 (R0)
  x0 += x1; x1 = rotl32(x1, 13); x1 ^= x0;
  x0 += x1; x1 = rotl32(x1, 15); x1 ^= x0;
  x0 += x1; x1 = rotl32(x1, 26); x1 ^= x0;
  x0 += x1; x1 = rotl32(x1, 6);  x1 ^= x0;
  x0 += ks2; x1 += k0 + 5u;
  o0 = x0; o1 = x1;
}

// gumbel for (step key (k0,k1), flat index j=b*64+s), partitionable threefry
__device__ __forceinline__ float jax_gumbel(uint32_t k0, uint32_t k1, int j) {
  uint32_t o0, o1;
  threefry2x32(k0, k1, 0u, (uint32_t)j, o0, o1);
  uint32_t bits = o0 ^ o1;
  uint32_t ub = (bits >> 9) | 0x3F800000u;
  float u = __uint_as_float(ub) - 1.0f;     // [0,1)
  u = fmaxf(u + TINYF, TINYF);              // uniform(tiny, 1)
  return -logf(-logf(u));
}

__device__ __forceinline__ float sigf(float x) {
  return 1.0f / (1.0f + expf(-x));
}

// ---------------- K0: fold dyn path through W_att2 ----------------
// Wd[h][d] = sum_k W_att[h,128+k]*dyn_w[k,d];  c[h] = sum_k W_att[h,128+k]*dyn_b[k]
__global__ void k0_dyn(const float* __restrict__ W_att, const float* __restrict__ dyn_w,
                       const float* __restrict__ dyn_b, float* __restrict__ Wd,
                       float* __restrict__ cv) {
  int h = threadIdx.x;  // 128
  float w0 = 0.f, w1 = 0.f, cc = 0.f;
  for (int k = 0; k < HN; ++k) {
    float w = W_att[h * 384 + 128 + k];
    w0 = fmaf(w, dyn_w[2 * k + 0], w0);
    w1 = fmaf(w, dyn_w[2 * k + 1], w1);
    cc = fmaf(w, dyn_b[k], cc);
  }
  Wd[2 * h] = w0; Wd[2 * h + 1] = w1; cv[h] = cc;
}

// ---------------- K1: x-chain (sequential, in_w in VGPRs) ----------------
// x_0 = in_w@SE[b,:,0]+in_b ; x_{i+1} = in_w@x_i + in_b.  X[i][b][h].
__global__ __launch_bounds__(128) void k1_xchain(const float* __restrict__ SE,
                                                 const float* __restrict__ in_w,
                                                 const float* __restrict__ in_b,
                                                 float* __restrict__ X) {
  __shared__ float xc[HN];
  int b = blockIdx.x, t = threadIdx.x;
  float wreg[HN];
#pragma unroll
  for (int k = 0; k < HN; k += 4) {
    float4 w4 = *(const float4*)(in_w + t * HN + k);
    wreg[k] = w4.x; wreg[k + 1] = w4.y; wreg[k + 2] = w4.z; wreg[k + 3] = w4.w;
  }
  float bt = in_b[t];
  xc[t] = SE[(b * HN + t) * SN + 0];
  __syncthreads();
  for (int i = 0; i < SN; ++i) {
    float a0 = 0.f, a1 = 0.f, a2 = 0.f, a3 = 0.f;
#pragma unroll
    for (int k = 0; k < HN; k += 4) {
      float4 x4 = *(const float4*)(xc + k);
      a0 = fmaf(wreg[k], x4.x, a0);
      a1 = fmaf(wreg[k + 1], x4.y, a1);
      a2 = fmaf(wreg[k + 2], x4.z, a2);
      a3 = fmaf(wreg[k + 3], x4.w, a3);
    }
    float acc = ((a0 + a1) + (a2 + a3)) + bt;
    X[(i * BN + b) * HN + t] = acc;
    __syncthreads();
    xc[t] = acc;
    __syncthreads();
  }
}

// ---------------- generic tall GEMM: C[n][m] = sum_k Xrows[n][k]*W[m][wofs+k] (+bias) ----
__global__ __launch_bounds__(256) void gemm_rows(const float* __restrict__ Xrows,
                                                 const float* __restrict__ W,
                                                 const float* __restrict__ bias,
                                                 float* __restrict__ Cout,
                                                 int wofs, int ldw, int ldc) {
  extern __shared__ float sm[];
  float* a_s = sm;             // [64][65]
  float* b_s = sm + 64 * 65;   // [128][65]
  int n0 = blockIdx.x * 64, mo = blockIdx.y * 128;
  int t = threadIdx.x;
  int tn = t & 15, tm = t >> 4;
  float acc[4][8];
#pragma unroll
  for (int j = 0; j < 4; ++j)
#pragma unroll
    for (int jj = 0; jj < 8; ++jj) acc[j][jj] = 0.f;

  for (int kb = 0; kb < 2; ++kb) {
    int k0 = kb * 64;
    __syncthreads();
    for (int idx = t; idx < 4096; idx += 256) {
      int n = idx >> 6, k = idx & 63;
      a_s[n * 65 + k] = Xrows[(n0 + n) * HN + k0 + k];
    }
    for (int idx = t; idx < 8192; idx += 256) {
      int m = idx >> 6, k = idx & 63;
      b_s[m * 65 + k] = W[(mo + m) * ldw + wofs + k0 + k];
    }
    __syncthreads();
#pragma unroll 4
    for (int k = 0; k < 64; ++k) {
      float av[4], bv[8];
#pragma unroll
      for (int j = 0; j < 4; ++j) av[j] = a_s[(tn * 4 + j) * 65 + k];
#pragma unroll
      for (int jj = 0; jj < 8; ++jj) bv[jj] = b_s[(tm * 8 + jj) * 65 + k];
#pragma unroll
      for (int j = 0; j < 4; ++j)
#pragma unroll
        for (int jj = 0; jj < 8; ++jj) acc[j][jj] = fmaf(av[j], bv[jj], acc[j][jj]);
    }
  }
#pragma unroll
  for (int j = 0; j < 4; ++j) {
    int n = n0 + tn * 4 + j;
#pragma unroll
    for (int jj = 0; jj < 8; ++jj) {
      int m = mo + tm * 8 + jj;
      float o = acc[j][jj];
      if (bias) o += bias[m];
      Cout[n * ldc + m] = o;
    }
  }
}

// ---------------- K5: Ust[(b*64+s)][h] = sum_k W_att[h][k]*SE[b][k][s] ----------------
__global__ __launch_bounds__(256) void gemm_se(const float* __restrict__ SE,
                                               const float* __restrict__ W,
                                               float* __restrict__ Cout) {
  extern __shared__ float sm[];
  float* a_s = sm;             // [64 s][65]
  float* b_s = sm + 64 * 65;   // [128 h][65]
  int b = blockIdx.x, t = threadIdx.x;
  int tn = t & 15, tm = t >> 4;
  float acc[4][8];
#pragma unroll
  for (int j = 0; j < 4; ++j)
#pragma unroll
    for (int jj = 0; jj < 8; ++jj) acc[j][jj] = 0.f;

  for (int kb = 0; kb < 2; ++kb) {
    int k0 = kb * 64;
    __syncthreads();
    for (int idx = t; idx < 4096; idx += 256) {
      int k = idx >> 6, s = idx & 63;
      a_s[s * 65 + k] = SE[(b * HN + k0 + k) * SN + s];
    }
    for (int idx = t; idx < 8192; idx += 256) {
      int m = idx >> 6, k = idx & 63;
      b_s[m * 65 + k] = W[m * 384 + k0 + k];
    }
    __syncthreads();
#pragma unroll 4
    for (int k = 0; k < 64; ++k) {
      float av[4], bv[8];
#pragma unroll
      for (int j = 0; j < 4; ++j) av[j] = a_s[(tn * 4 + j) * 65 + k];
#pragma unroll
      for (int jj = 0; jj < 8; ++jj) bv[jj] = b_s[(tm * 8 + jj) * 65 + k];
#pragma unroll
      for (int j = 0; j < 4; ++j)
#pragma unroll
        for (int jj = 0; jj < 8; ++jj) acc[j][jj] = fmaf(av[j], bv[jj], acc[j][jj]);
    }
  }
#pragma unroll
  for (int j = 0; j < 4; ++j) {
    int s = tn * 4 + j;
#pragma unroll
    for (int jj = 0; jj < 8; ++jj) {
      int m = tm * 8 + jj;
      Cout[(b * SN + s) * HN + m] = acc[j][jj];
    }
  }
}

// ---------------- K3: h-chain (sequential GRU, w_hh rows in VGPRs) ----------------
__global__ __launch_bounds__(384) void k3_hchain(const float* __restrict__ GI,
                                                 const float* __restrict__ w_hh,
                                                 const float* __restrict__ b_hh,
                                                 float* __restrict__ Hs) {
  __shared__ float hc[HN];
  __shared__ float gsh[384];
  int b = blockIdx.x, t = threadIdx.x;
  float wreg[HN];
#pragma unroll
  for (int k = 0; k < HN; k += 4) {
    float4 w4 = *(const float4*)(w_hh + t * HN + k);
    wreg[k] = w4.x; wreg[k + 1] = w4.y; wreg[k + 2] = w4.z; wreg[k + 3] = w4.w;
  }
  float bt = b_hh[t];
  if (t < HN) hc[t] = 0.f;
  __syncthreads();
  for (int i = 0; i < SN; ++i) {
    float a0 = 0.f, a1 = 0.f, a2 = 0.f, a3 = 0.f;
#pragma unroll
    for (int k = 0; k < HN; k += 4) {
      float4 x4 = *(const float4*)(hc + k);
      a0 = fmaf(wreg[k], x4.x, a0);
      a1 = fmaf(wreg[k + 1], x4.y, a1);
      a2 = fmaf(wreg[k + 2], x4.z, a2);
      a3 = fmaf(wreg[k + 3], x4.w, a3);
    }
    gsh[t] = ((a0 + a1) + (a2 + a3)) + bt;
    __syncthreads();
    if (t < HN) {
      const float* gi = GI + (i * BN + b) * 384;
      float r = sigf(gi[t] + gsh[t]);
      float z = sigf(gi[HN + t] + gsh[HN + t]);
      float nn = tanhf(gi[2 * HN + t] + r * gsh[2 * HN + t]);
      float hnew = (1.0f - z) * nn + z * hc[t];
      Hs[(i * BN + b) * HN + t] = hnew;
      hc[t] = hnew;
    }
    __syncthreads();
  }
}

// ---------------- K6: score tensor P[b][i][s] ----------------
__global__ __launch_bounds__(256) void k6_scores(const float* __restrict__ Ust,
                                                 const float* __restrict__ WhC,
                                                 const float* __restrict__ dynamic,
                                                 const float* __restrict__ Wd,
                                                 const float* __restrict__ cv,
                                                 const float* __restrict__ v_att,
                                                 float* __restrict__ Pg) {
  extern __shared__ float sm[];
  float* U  = sm;          // [128 h][64 s]  (32KB)
  float* Wh = sm + 8192;   // [64 i][128 h]  (32KB)
  int b = blockIdx.x, t = threadIdx.x;
  for (int idx = t; idx < 8192; idx += 256) {
    int s = idx & 63, h = idx >> 6;
    U[h * 64 + s] = Ust[(b * SN + s) * HN + h];
  }
  for (int idx = t; idx < 8192; idx += 256) {
    int h = idx & 127, i = idx >> 7;
    Wh[i * HN + h] = WhC[(i * BN + b) * HN + h];
  }
  __syncthreads();
  for (int idx = t; idx < 8192; idx += 256) {
    int s = idx & 63, h = idx >> 6;
    float d0 = dynamic[(b * 2 + 0) * SN + s];
    float d1 = dynamic[(b * 2 + 1) * SN + s];
    U[h * 64 + s] += Wd[2 * h] * d0 + Wd[2 * h + 1] * d1 + cv[h];
  }
  __syncthreads();
  int s = t & 63, ib = t >> 6;
  for (int it = 0; it < 16; ++it) {
    int i = it * 4 + ib;
    float acc = 0.f;
#pragma unroll 8
    for (int h = 0; h < HN; ++h) {
      float x = U[h * 64 + s] + Wh[i * HN + h];
      acc = fmaf(v_att[h], tanhf(x), acc);
    }
    Pg[b * 4096 + i * 64 + s] = acc;
  }
}

// ---------------- K7: sampling (one wave per batch element) ----------------
__global__ __launch_bounds__(256) void k7_sample(const float* __restrict__ Pg,
                                                 float* __restrict__ out) {
  extern __shared__ float sm[];
  float* Pl = sm;          // 4096
  float* Gl = sm + 4096;   // 4096
  uint32_t* kk0 = (uint32_t*)(Gl + 4096);  // 64
  uint32_t* kk1 = kk0 + 64;                // 64
  int b = blockIdx.x, t = threadIdx.x;
  for (int idx = t; idx < 4096; idx += 256) Pl[idx] = Pg[b * 4096 + idx];
  if (t < 64) {
    uint32_t o0, o1;
    threefry2x32(0u, 42u, 0u, (uint32_t)t, o0, o1);  // fold_in(key(42), i=t)
    kk0[t] = o0; kk1[t] = o1;
  }
  __syncthreads();
  for (int idx = t; idx < 4096; idx += 256) {
    int i = idx >> 6, s = idx & 63;
    Gl[idx] = jax_gumbel(kk0[i], kk1[i], b * 64 + s);
  }
  __syncthreads();
  if (t < 64) {
    int s = t;
    bool visited = false;
    for (int i = 0; i < SN; ++i) {
      float score = Pl[i * 64 + s];
      bool allowed = (i == 0) ? (s == 0) : (!visited);
      float logit = allowed ? score : NEGV;
      float z = logit + Gl[i * 64 + s];
      float bz = z; int bi = s;
#pragma unroll
      for (int off = 32; off > 0; off >>= 1) {
        float oz = __shfl_xor(bz, off);
        int oi = __shfl_xor(bi, off);
        if (oz > bz || (oz == bz && oi < bi)) { bz = oz; bi = oi; }
      }
      int ptr = bi;
      float m = logit;
#pragma unroll
      for (int off = 32; off > 0; off >>= 1) m = fmaxf(m, __shfl_xor(m, off));
      float e = expf(logit - m);
      float sum = e;
#pragma unroll
      for (int off = 32; off > 0; off >>= 1) sum += __shfl_xor(sum, off);
      float chosen = __shfl(logit, ptr);
      float logp = (chosen - m) - logf(sum);
      if (s == ptr) visited = true;
      if (s == 0) {
        out[b * SN + i] = (float)ptr;                 // tours.T (B,S)
        out[BN * SN + b * SN + i] = logp;             // logps.T (B,S)
      }
    }
  }
}

// ---------------- launch ----------------
extern "C" void kernel_launch(void* const* d_in, const int* in_sizes, int n_in,
                              void* d_out, int out_size, void* d_ws, size_t ws_size,
                              hipStream_t stream) {
  const float* SE    = (const float*)d_in[1];   // static_embeddings (B,H,S)
  const float* dynam = (const float*)d_in[2];   // dynamic (B,2,S)
  const float* dyn_w = (const float*)d_in[3];   // (H,2)
  const float* dyn_b = (const float*)d_in[4];   // (H,)
  const float* in_w  = (const float*)d_in[5];   // (H,H)
  const float* in_b  = (const float*)d_in[6];   // (H,)
  const float* w_ih  = (const float*)d_in[7];   // (3H,H)
  const float* w_hh  = (const float*)d_in[8];   // (3H,H)
  const float* b_ih  = (const float*)d_in[9];   // (3H,)
  const float* b_hh  = (const float*)d_in[10];  // (3H,)
  const float* W_att = (const float*)d_in[11];  // (H,3H)
  const float* v_att = (const float*)d_in[12];  // (H,)
  float* out = (float*)d_out;
  float* ws = (float*)d_ws;

  float* X   = ws;
  float* GI  = ws + 2097152;
  float* WhC = GI;
  float* Ust = ws + 4194304;
  float* Wd  = ws + 8388608;
  float* cv  = Wd + 256;
  float* Hs  = X;
  float* P   = X;

  hipLaunchKernelGGL(k0_dyn, dim3(1), dim3(128), 0, stream, W_att, dyn_w, dyn_b, Wd, cv);
  hipLaunchKernelGGL(k1_xchain, dim3(BN), dim3(128), 0, stream, SE, in_w, in_b, X);
  hipLaunchKernelGGL(gemm_rows, dim3(256, 3), dim3(256), 49920, stream,
                     X, w_ih, b_ih, GI, 0, HN, 384);
  hipLaunchKernelGGL(k3_hchain, dim3(BN), dim3(384), 0, stream, GI, w_hh, b_hh, Hs);
  hipLaunchKernelGGL(gemm_rows, dim3(256, 1), dim3(256), 49920, stream,
                     Hs, W_att, (const float*)nullptr, WhC, 256, 384, HN);
  hipLaunchKernelGGL(gemm_se, dim3(BN), dim3(256), 49920, stream, SE, W_att, Ust);
  hipLaunchKernelGGL(k6_scores, dim3(BN), dim3(256), 65536, stream,
                     Ust, WhC, dynam, Wd, cv, v_att, P);
  hipLaunchKernelGGL(k7_sample, dim3(BN), dim3(256), 33280, stream, P, out);
}

// Round 3
// 420.409 us; speedup vs baseline: 1.5084x; 1.5084x over previous
//
#include <hip/hip_runtime.h>
#include <stdint.h>

// PointerNetwork forward, MI355X/gfx950.
// x-chain and h-chain are sampling-independent; scores for unvisited slots
// don't depend on WHICH slots are visited => precompute all, sample cheaply.
// B=256, S=64, H=128.
// RNG: JAX threefry2x32 partitionable mode: bits = o0^o1 of tf(key,(0,j)).

#define BN 256
#define SN 64
#define HN 128
#define NEGV (-1.0e9f)
#define TINYF 1.17549435e-38f

__device__ __forceinline__ uint32_t rotl32(uint32_t v, int d) {
  return (v << d) | (v >> (32 - d));
}

__device__ __forceinline__ void threefry2x32(uint32_t k0, uint32_t k1,
                                             uint32_t x0, uint32_t x1,
                                             uint32_t& o0, uint32_t& o1) {
  uint32_t ks2 = k0 ^ k1 ^ 0x1BD11BDAu;
  x0 += k0; x1 += k1;
  x0 += x1; x1 = rotl32(x1, 13); x1 ^= x0;
  x0 += x1; x1 = rotl32(x1, 15); x1 ^= x0;
  x0 += x1; x1 = rotl32(x1, 26); x1 ^= x0;
  x0 += x1; x1 = rotl32(x1, 6);  x1 ^= x0;
  x0 += k1; x1 += ks2 + 1u;
  x0 += x1; x1 = rotl32(x1, 17); x1 ^= x0;
  x0 += x1; x1 = rotl32(x1, 29); x1 ^= x0;
  x0 += x1; x1 = rotl32(x1, 16); x1 ^= x0;
  x0 += x1; x1 = rotl32(x1, 24); x1 ^= x0;
  x0 += ks2; x1 += k0 + 2u;
  x0 += x1; x1 = rotl32(x1, 13); x1 ^= x0;
  x0 += x1; x1 = rotl32(x1, 15); x1 ^= x0;
  x0 += x1; x1 = rotl32(x1, 26); x1 ^= x0;
  x0 += x1; x1 = rotl32(x1, 6);  x1 ^= x0;
  x0 += k0; x1 += k1 + 3u;
  x0 += x1; x1 = rotl32(x1, 17); x1 ^= x0;
  x0 += x1; x1 = rotl32(x1, 29); x1 ^= x0;
  x0 += x1; x1 = rotl32(x1, 16); x1 ^= x0;
  x0 += x1; x1 = rotl32(x1, 24); x1 ^= x0;
  x0 += k1; x1 += ks2 + 4u;
  x0 += x1; x1 = rotl32(x1, 13); x1 ^= x0;
  x0 += x1; x1 = rotl32(x1, 15); x1 ^= x0;
  x0 += x1; x1 = rotl32(x1, 26); x1 ^= x0;
  x0 += x1; x1 = rotl32(x1, 6);  x1 ^= x0;
  x0 += ks2; x1 += k0 + 5u;
  o0 = x0; o1 = x1;
}

__device__ __forceinline__ float jax_gumbel(uint32_t k0, uint32_t k1, int j) {
  uint32_t o0, o1;
  threefry2x32(k0, k1, 0u, (uint32_t)j, o0, o1);
  uint32_t bits = o0 ^ o1;
  uint32_t ub = (bits >> 9) | 0x3F800000u;
  float u = __uint_as_float(ub) - 1.0f;
  u = fmaxf(u + TINYF, TINYF);
  return -logf(-logf(u));
}

// fast tanh: (1-e)/(1+e), e=exp(-2|x|) in (0,1] (no overflow); ~2ulp
__device__ __forceinline__ float ftanh(float x) {
  float ax = fabsf(x);
  float e = __expf(-2.0f * ax);
  float r = (1.0f - e) * __builtin_amdgcn_rcpf(1.0f + e);
  return copysignf(r, x);
}

__device__ __forceinline__ float fsig(float x) {
  return __builtin_amdgcn_rcpf(1.0f + __expf(-x));
}

// ---------------- K0: fold dyn path + step keys ----------------
__global__ void k0_dyn(const float* __restrict__ W_att, const float* __restrict__ dyn_w,
                       const float* __restrict__ dyn_b, float* __restrict__ Wd,
                       float* __restrict__ cv, uint32_t* __restrict__ keys) {
  int h = threadIdx.x;  // 128
  if (h < 64) {  // step keys: fold_in(key(42), i) = threefry((0,42),(0,i))
    uint32_t o0, o1;
    threefry2x32(0u, 42u, 0u, (uint32_t)h, o0, o1);
    keys[2 * h] = o0; keys[2 * h + 1] = o1;
  }
  float w0 = 0.f, w1 = 0.f, cc = 0.f;
  for (int k = 0; k < HN; ++k) {
    float w = W_att[h * 384 + 128 + k];
    w0 = fmaf(w, dyn_w[2 * k + 0], w0);
    w1 = fmaf(w, dyn_w[2 * k + 1], w1);
    cc = fmaf(w, dyn_b[k], cc);
  }
  Wd[2 * h] = w0; Wd[2 * h + 1] = w1; cv[h] = cc;
}

// ---------------- K1: x-chain ----------------
__global__ __launch_bounds__(128) void k1_xchain(const float* __restrict__ SE,
                                                 const float* __restrict__ in_w,
                                                 const float* __restrict__ in_b,
                                                 float* __restrict__ X) {
  __shared__ float xc[HN];
  int b = blockIdx.x, t = threadIdx.x;
  float wreg[HN];
#pragma unroll
  for (int k = 0; k < HN; k += 4) {
    float4 w4 = *(const float4*)(in_w + t * HN + k);
    wreg[k] = w4.x; wreg[k + 1] = w4.y; wreg[k + 2] = w4.z; wreg[k + 3] = w4.w;
  }
  float bt = in_b[t];
  xc[t] = SE[(b * HN + t) * SN + 0];
  __syncthreads();
  for (int i = 0; i < SN; ++i) {
    float a0 = 0.f, a1 = 0.f, a2 = 0.f, a3 = 0.f;
#pragma unroll
    for (int k = 0; k < HN; k += 4) {
      float4 x4 = *(const float4*)(xc + k);
      a0 = fmaf(wreg[k], x4.x, a0);
      a1 = fmaf(wreg[k + 1], x4.y, a1);
      a2 = fmaf(wreg[k + 2], x4.z, a2);
      a3 = fmaf(wreg[k + 3], x4.w, a3);
    }
    float acc = ((a0 + a1) + (a2 + a3)) + bt;
    X[(i * BN + b) * HN + t] = acc;
    __syncthreads();
    xc[t] = acc;
    __syncthreads();
  }
}

// ---------------- generic GEMM: C[n][m] = sum_k Xrows[n][k]*W[m][wofs+k] ----
__global__ __launch_bounds__(256) void gemm_rows(const float* __restrict__ Xrows,
                                                 const float* __restrict__ W,
                                                 const float* __restrict__ bias,
                                                 float* __restrict__ Cout,
                                                 int wofs, int ldw, int ldc) {
  extern __shared__ float sm[];
  float* a_s = sm;             // [64][65]
  float* b_s = sm + 64 * 65;   // [128][65]
  int n0 = blockIdx.x * 64, mo = blockIdx.y * 128;
  int t = threadIdx.x;
  int tn = t & 15, tm = t >> 4;
  float acc[4][8];
#pragma unroll
  for (int j = 0; j < 4; ++j)
#pragma unroll
    for (int jj = 0; jj < 8; ++jj) acc[j][jj] = 0.f;

  for (int kb = 0; kb < 2; ++kb) {
    int k0 = kb * 64;
    __syncthreads();
    for (int idx = t; idx < 4096; idx += 256) {
      int n = idx >> 6, k = idx & 63;
      a_s[n * 65 + k] = Xrows[(n0 + n) * HN + k0 + k];
    }
    for (int idx = t; idx < 8192; idx += 256) {
      int m = idx >> 6, k = idx & 63;
      b_s[m * 65 + k] = W[(mo + m) * ldw + wofs + k0 + k];
    }
    __syncthreads();
#pragma unroll 4
    for (int k = 0; k < 64; ++k) {
      float av[4], bv[8];
#pragma unroll
      for (int j = 0; j < 4; ++j) av[j] = a_s[(tn * 4 + j) * 65 + k];
#pragma unroll
      for (int jj = 0; jj < 8; ++jj) bv[jj] = b_s[(tm * 8 + jj) * 65 + k];
#pragma unroll
      for (int j = 0; j < 4; ++j)
#pragma unroll
        for (int jj = 0; jj < 8; ++jj) acc[j][jj] = fmaf(av[j], bv[jj], acc[j][jj]);
    }
  }
#pragma unroll
  for (int j = 0; j < 4; ++j) {
    int n = n0 + tn * 4 + j;
#pragma unroll
    for (int jj = 0; jj < 8; ++jj) {
      int m = mo + tm * 8 + jj;
      float o = acc[j][jj];
      if (bias) o += bias[m];
      Cout[n * ldc + m] = o;
    }
  }
}

// ---------------- K5: Ust[(b*64+s)][h] = sum_k W_att[h][k]*SE[b][k][s] ----
__global__ __launch_bounds__(256) void gemm_se(const float* __restrict__ SE,
                                               const float* __restrict__ W,
                                               float* __restrict__ Cout) {
  extern __shared__ float sm[];
  float* a_s = sm;             // [64 s][65]
  float* b_s = sm + 64 * 65;   // [128 h][65]
  int b = blockIdx.x, t = threadIdx.x;
  int tn = t & 15, tm = t >> 4;
  float acc[4][8];
#pragma unroll
  for (int j = 0; j < 4; ++j)
#pragma unroll
    for (int jj = 0; jj < 8; ++jj) acc[j][jj] = 0.f;

  for (int kb = 0; kb < 2; ++kb) {
    int k0 = kb * 64;
    __syncthreads();
    for (int idx = t; idx < 4096; idx += 256) {
      int k = idx >> 6, s = idx & 63;
      a_s[s * 65 + k] = SE[(b * HN + k0 + k) * SN + s];
    }
    for (int idx = t; idx < 8192; idx += 256) {
      int m = idx >> 6, k = idx & 63;
      b_s[m * 65 + k] = W[m * 384 + k0 + k];
    }
    __syncthreads();
#pragma unroll 4
    for (int k = 0; k < 64; ++k) {
      float av[4], bv[8];
#pragma unroll
      for (int j = 0; j < 4; ++j) av[j] = a_s[(tn * 4 + j) * 65 + k];
#pragma unroll
      for (int jj = 0; jj < 8; ++jj) bv[jj] = b_s[(tm * 8 + jj) * 65 + k];
#pragma unroll
      for (int j = 0; j < 4; ++j)
#pragma unroll
        for (int jj = 0; jj < 8; ++jj) acc[j][jj] = fmaf(av[j], bv[jj], acc[j][jj]);
    }
  }
#pragma unroll
  for (int j = 0; j < 4; ++j) {
    int s = tn * 4 + j;
#pragma unroll
    for (int jj = 0; jj < 8; ++jj) {
      int m = tm * 8 + jj;
      Cout[(b * SN + s) * HN + m] = acc[j][jj];
    }
  }
}

// ---------------- K3: h-chain (GRU) with GI prefetch ----------------
__global__ __launch_bounds__(384) void k3_hchain(const float* __restrict__ GI,
                                                 const float* __restrict__ w_hh,
                                                 const float* __restrict__ b_hh,
                                                 float* __restrict__ Hs) {
  __shared__ float hc[HN];
  __shared__ float gsh[384];
  __shared__ float gish[384];
  int b = blockIdx.x, t = threadIdx.x;
  float wreg[HN];
#pragma unroll
  for (int k = 0; k < HN; k += 4) {
    float4 w4 = *(const float4*)(w_hh + t * HN + k);
    wreg[k] = w4.x; wreg[k + 1] = w4.y; wreg[k + 2] = w4.z; wreg[k + 3] = w4.w;
  }
  float bt = b_hh[t];
  if (t < HN) hc[t] = 0.f;
  __syncthreads();
  for (int i = 0; i < SN; ++i) {
    float gval = GI[(i * BN + b) * 384 + t];  // issued early; overlaps matvec
    float a0 = 0.f, a1 = 0.f, a2 = 0.f, a3 = 0.f;
#pragma unroll
    for (int k = 0; k < HN; k += 4) {
      float4 x4 = *(const float4*)(hc + k);
      a0 = fmaf(wreg[k], x4.x, a0);
      a1 = fmaf(wreg[k + 1], x4.y, a1);
      a2 = fmaf(wreg[k + 2], x4.z, a2);
      a3 = fmaf(wreg[k + 3], x4.w, a3);
    }
    gsh[t] = ((a0 + a1) + (a2 + a3)) + bt;
    gish[t] = gval;
    __syncthreads();
    if (t < HN) {
      float r = fsig(gish[t] + gsh[t]);
      float z = fsig(gish[HN + t] + gsh[HN + t]);
      float nn = ftanh(gish[2 * HN + t] + r * gsh[2 * HN + t]);
      float hnew = (1.0f - z) * nn + z * hc[t];
      Hs[(i * BN + b) * HN + t] = hnew;
      hc[t] = hnew;
    }
    __syncthreads();
  }
}

// ---------------- K6: scores P[b][i][s], 8 i per block ----------------
__global__ __launch_bounds__(256) void k6_scores(const float* __restrict__ Ust,
                                                 const float* __restrict__ WhC,
                                                 const float* __restrict__ dynamic,
                                                 const float* __restrict__ Wd,
                                                 const float* __restrict__ cv,
                                                 const float* __restrict__ v_att,
                                                 float* __restrict__ Pg) {
  __shared__ float U[HN * 65];   // [h][s] padded (+1 bank skew)
  __shared__ float Wh[8 * HN];
  __shared__ float sv[HN];
  int b = blockIdx.x, iq = blockIdx.y, t = threadIdx.x;
  // stage U coalesced: idx = s*128+h -> U[h*65+s] (conflict-free both ways)
#pragma unroll
  for (int p = 0; p < 32; ++p) {
    int idx = p * 256 + t;
    int s = idx >> 7, h = idx & 127;
    float u = Ust[(b * SN + s) * HN + h];
    float d0 = dynamic[(b * 2 + 0) * SN + s];
    float d1 = dynamic[(b * 2 + 1) * SN + s];
    u += Wd[2 * h] * d0 + Wd[2 * h + 1] * d1 + cv[h];
    U[h * 65 + s] = u;
  }
#pragma unroll
  for (int p = 0; p < 4; ++p) {
    int idx = p * 256 + t;
    int i = idx >> 7, h = idx & 127;
    Wh[i * HN + h] = WhC[((iq * 8 + i) * BN + b) * HN + h];
  }
  if (t < HN) sv[t] = v_att[t];
  __syncthreads();
  int s = t & 63, w = t >> 6;   // wave w handles i = iq*8 + w*2 + {0,1}
  float acc0 = 0.f, acc1 = 0.f;
  for (int h = 0; h < HN; h += 4) {
    float u0 = U[(h + 0) * 65 + s];
    float u1 = U[(h + 1) * 65 + s];
    float u2 = U[(h + 2) * 65 + s];
    float u3 = U[(h + 3) * 65 + s];
    float4 v4 = *(const float4*)&sv[h];
    float4 wa = *(const float4*)&Wh[(w * 2 + 0) * HN + h];
    acc0 = fmaf(v4.x, ftanh(u0 + wa.x), acc0);
    acc0 = fmaf(v4.y, ftanh(u1 + wa.y), acc0);
    acc0 = fmaf(v4.z, ftanh(u2 + wa.z), acc0);
    acc0 = fmaf(v4.w, ftanh(u3 + wa.w), acc0);
    float4 wb = *(const float4*)&Wh[(w * 2 + 1) * HN + h];
    acc1 = fmaf(v4.x, ftanh(u0 + wb.x), acc1);
    acc1 = fmaf(v4.y, ftanh(u1 + wb.y), acc1);
    acc1 = fmaf(v4.z, ftanh(u2 + wb.z), acc1);
    acc1 = fmaf(v4.w, ftanh(u3 + wb.w), acc1);
  }
  int i0 = iq * 8 + w * 2;
  Pg[b * 4096 + (i0 + 0) * 64 + s] = acc0;
  Pg[b * 4096 + (i0 + 1) * 64 + s] = acc1;
}

// ---------------- KG: gumbels (fully parallel) ----------------
__global__ __launch_bounds__(256) void kG_gumbel(const uint32_t* __restrict__ keys,
                                                 float* __restrict__ G) {
  int idx = blockIdx.x * 256 + threadIdx.x;  // b*4096 + i*64 + s
  int b = idx >> 12;
  int i = (idx >> 6) & 63;
  int s = idx & 63;
  G[idx] = jax_gumbel(keys[2 * i], keys[2 * i + 1], b * 64 + s);
}

// ---------------- K7: sampling (one wave per batch element) ----------------
__global__ __launch_bounds__(256) void k7_sample(const float* __restrict__ Pg,
                                                 const float* __restrict__ Gg,
                                                 float* __restrict__ out) {
  __shared__ float Pl[4096];
  __shared__ float Gl[4096];
  int b = blockIdx.x, t = threadIdx.x;
#pragma unroll
  for (int p = 0; p < 4; ++p) {
    ((float4*)Pl)[p * 256 + t] = ((const float4*)(Pg + b * 4096))[p * 256 + t];
    ((float4*)Gl)[p * 256 + t] = ((const float4*)(Gg + b * 4096))[p * 256 + t];
  }
  __syncthreads();
  if (t < 64) {
    int s = t;
    bool visited = false;
    for (int i = 0; i < SN; ++i) {
      float score = Pl[i * 64 + s];
      bool allowed = (i == 0) ? (s == 0) : (!visited);
      float logit = allowed ? score : NEGV;
      float z = logit + Gl[i * 64 + s];
      float bz = z; int bi = s;
#pragma unroll
      for (int off = 32; off > 0; off >>= 1) {
        float oz = __shfl_xor(bz, off);
        int oi = __shfl_xor(bi, off);
        if (oz > bz || (oz == bz && oi < bi)) { bz = oz; bi = oi; }
      }
      int ptr = bi;
      float m = logit;
#pragma unroll
      for (int off = 32; off > 0; off >>= 1) m = fmaxf(m, __shfl_xor(m, off));
      float e = expf(logit - m);
      float sum = e;
#pragma unroll
      for (int off = 32; off > 0; off >>= 1) sum += __shfl_xor(sum, off);
      float chosen = __shfl(logit, ptr);
      float logp = (chosen - m) - logf(sum);
      if (s == ptr) visited = true;
      if (s == 0) {
        out[b * SN + i] = (float)ptr;
        out[BN * SN + b * SN + i] = logp;
      }
    }
  }
}

// ---------------- launch ----------------
extern "C" void kernel_launch(void* const* d_in, const int* in_sizes, int n_in,
                              void* d_out, int out_size, void* d_ws, size_t ws_size,
                              hipStream_t stream) {
  const float* SE    = (const float*)d_in[1];
  const float* dynam = (const float*)d_in[2];
  const float* dyn_w = (const float*)d_in[3];
  const float* dyn_b = (const float*)d_in[4];
  const float* in_w  = (const float*)d_in[5];
  const float* in_b  = (const float*)d_in[6];
  const float* w_ih  = (const float*)d_in[7];
  const float* w_hh  = (const float*)d_in[8];
  const float* b_ih  = (const float*)d_in[9];
  const float* b_hh  = (const float*)d_in[10];
  const float* W_att = (const float*)d_in[11];
  const float* v_att = (const float*)d_in[12];
  float* out = (float*)d_out;
  float* ws = (float*)d_ws;

  // workspace (floats):
  //  [0, 2M)        X (K1->K2), Hs (K3->K4), P (K6->K7)
  //  [2M, 8.39M)    GI (K2->K3); after K3: WhC @2M, Ust @4.19M, G @6.29M
  //  [8.39M, +384)  Wd, cv;  keys (uint32) after
  float* X   = ws;
  float* GI  = ws + 2097152;
  float* WhC = GI;
  float* Ust = ws + 4194304;
  float* G   = ws + 6291456;
  float* Wd  = ws + 8388608;
  float* cv  = Wd + 256;
  uint32_t* keys = (uint32_t*)(cv + 128);
  float* Hs  = X;
  float* P   = X;

  hipLaunchKernelGGL(k0_dyn, dim3(1), dim3(128), 0, stream, W_att, dyn_w, dyn_b, Wd, cv, keys);
  hipLaunchKernelGGL(k1_xchain, dim3(BN), dim3(128), 0, stream, SE, in_w, in_b, X);
  hipLaunchKernelGGL(gemm_rows, dim3(256, 3), dim3(256), 49920, stream,
                     X, w_ih, b_ih, GI, 0, HN, 384);
  hipLaunchKernelGGL(k3_hchain, dim3(BN), dim3(384), 0, stream, GI, w_hh, b_hh, Hs);
  hipLaunchKernelGGL(kG_gumbel, dim3(4096), dim3(256), 0, stream, keys, G);
  hipLaunchKernelGGL(gemm_rows, dim3(256, 1), dim3(256), 49920, stream,
                     Hs, W_att, (const float*)nullptr, WhC, 256, 384, HN);
  hipLaunchKernelGGL(gemm_se, dim3(BN), dim3(256), 49920, stream, SE, W_att, Ust);
  hipLaunchKernelGGL(k6_scores, dim3(BN, 8), dim3(256), 0, stream,
                     Ust, WhC, dynam, Wd, cv, v_att, P);
  hipLaunchKernelGGL(k7_sample, dim3(BN), dim3(256), 0, stream, P, G, out);
}